// Round 6
// baseline (176.278 us; speedup 1.0000x reference)
//
#include <hip/hip_runtime.h>

// Problem constants (from reference setup_inputs):
//   B=4, H=4, S=8, N=32768, W=32 -> P=W^3=32768, C=128, F=C/H=32
#define P_W3 32768
#define F_DIM 32
#define S_DIM 8
#define N_DIM 32768
#define BH_DIM 16   // B*H
#define NXCD 8      // MI355X XCD count

typedef _Float16 half8 __attribute__((ext_vector_type(8)));  // 16 B
typedef float    f32x4 __attribute__((ext_vector_type(4)));  // 16 B, clang-native

// ---------------------------------------------------------------------------
// XCD-pinned bh decomposition: 8192 blocks = 16 bh x 512 tiles of 64.
//   xcd = blk & 7; slot = blk >> 3; bh = 2*xcd + (slot >> 9)
// Per-XCD live T working set = one 2 MiB bh slice (fits 4 MiB L2).
// Verified round 1: gather FETCH 133 -> 34 MB.
// ---------------------------------------------------------------------------
__device__ __forceinline__ void xcd_bh_tile(int blk, int& bh, int& tile) {
    const int xcd  = blk & (NXCD - 1);
    const int slot = blk >> 3;          // 0..1023
    bh   = 2 * xcd + (slot >> 9);       // 0..15
    tile = slot & 511;                  // 0..511
}

// ---------------------------------------------------------------------------
// Kernel 1: transpose + convert conv [bh, f, p] fp32 -> T [bh, p, f] fp16.
// Streaming-bound at ~18 us vs 16 us floor (96 MB at ~6 TB/s) -- unchanged.
// ---------------------------------------------------------------------------
__global__ __launch_bounds__(256) void transpose_f16_kernel(
    const float* __restrict__ conv, _Float16* __restrict__ T) {
    int bh, pt;
    xcd_bh_tile(blockIdx.x, bh, pt);
    const int p0 = pt * 64;

    __shared__ float tile[F_DIM][65];         // stride 65: 2-way max on readout

    const float* src = conv + (size_t)bh * F_DIM * P_W3 + p0;
    {
        const int pp = (threadIdx.x & 15) * 4;
        const int f  = threadIdx.x >> 4;      // 0..15
#pragma unroll
        for (int k = 0; k < 2; ++k) {
            const f32x4 v = __builtin_nontemporal_load(
                (const f32x4*)(src + (size_t)(f + 16 * k) * P_W3 + pp));
            tile[f + 16 * k][pp + 0] = v.x;
            tile[f + 16 * k][pp + 1] = v.y;
            tile[f + 16 * k][pp + 2] = v.z;
            tile[f + 16 * k][pp + 3] = v.w;
        }
    }
    __syncthreads();

    _Float16* dst = T + ((size_t)bh * P_W3 + p0) * F_DIM;
    {
        const int f0 = (threadIdx.x & 3) * 8;
        const int p  = threadIdx.x >> 2;      // 0..63
        half8 hv;
#pragma unroll
        for (int j = 0; j < 8; ++j) hv[j] = (_Float16)tile[f0 + j][p];
        *(half8*)(dst + (size_t)p * F_DIM + f0) = hv;   // 64B/4 lanes contiguous
    }
}

// ---------------------------------------------------------------------------
// Kernel 2: gather, spill-free forced-MLP version.
// Round-5 post-mortem: 16 forced gather dests (64 VGPR) spilled to scratch
// (VGPR_Count=56 < 64 needed) -> occupancy capped at 33%, no gain. This round:
//   - 64-n blocks, 8 gathers/thread: 32 forced dest VGPRs, total ~70, no spill
//   - NO input staging / no pre-gather barrier: 8 idx + 8 w loaded directly
//     as a volatile-asm batch (idx issued first). vmcnt(8) retires exactly
//     the idx batch (w still in flight), then 8 gathers issue, vmcnt(0)
//     drains w+gathers before FMA. sched_barrier(0) after each waitcnt
//     (rule #18: register-only consumers otherwise hoist past asm waitcnt).
//   - LDS only for the 8.4 KB output transpose -> ~7 waves/SIMD resident.
// Serial path per wave: 1 HBM latency + 1 L2 latency, ~8x less sync than R5.
// No other VMEM ops exist between the asm loads and the waitcnts, so the
// vmcnt counts are exact.
// ---------------------------------------------------------------------------
__global__ __launch_bounds__(256) void gather_f16_kernel(
    const float* __restrict__ lc, const int* __restrict__ idx,
    const _Float16* __restrict__ T, float* __restrict__ out) {
    int bh, nt;
    xcd_bh_tile(blockIdx.x, bh, nt);
    const int nb = nt * 64;
    const int t  = threadIdx.x;
    const int q  = t & 3;                     // 16B sub-chunk 0..3
    const int nl = t >> 2;                    // local n 0..63
    const int n  = nb + nl;

    // Wave-uniform bases (SGPR pairs in the asm); per-thread part in voffset.
    const int*      ibase = idx + (size_t)bh * S_DIM * N_DIM;
    const float*    wbase = lc  + (size_t)bh * S_DIM * N_DIM;
    const _Float16* Tbase = T   + (size_t)bh * P_W3 * F_DIM;

    // Phase 1: 8 idx loads then 8 w loads, all 16 in flight (idx oldest).
    // 4 lanes share each address; coalescer dedups, traffic unchanged.
    int   ids[S_DIM];
    float wts[S_DIM];
#pragma unroll
    for (int s = 0; s < S_DIM; ++s) {
        const int voff = (n + s * N_DIM) * 4;           // < 1 MiB, fits u32
        asm volatile("global_load_dword %0, %1, %2 nt"
                     : "=v"(ids[s]) : "v"(voff), "s"(ibase) : "memory");
    }
#pragma unroll
    for (int s = 0; s < S_DIM; ++s) {
        const int voff = (n + s * N_DIM) * 4;
        asm volatile("global_load_dword %0, %1, %2 nt"
                     : "=v"(wts[s]) : "v"(voff), "s"(wbase) : "memory");
    }

    // Wait for the idx batch only (oldest 8); w loads keep flying.
    asm volatile("s_waitcnt vmcnt(8)" ::: "memory");
    __builtin_amdgcn_sched_barrier(0);

    // Phase 2: 8 forced gathers (16 B per lane, 4 lanes per 64 B row).
    f32x4 g[S_DIM];
#pragma unroll
    for (int s = 0; s < S_DIM; ++s) {
        const int voff = (ids[s] << 6) + (q << 4);      // id*64B + q*16B
        asm volatile("global_load_dwordx4 %0, %1, %2"
                     : "=v"(g[s]) : "v"(voff), "s"(Tbase) : "memory");
    }
    asm volatile("s_waitcnt vmcnt(0)" ::: "memory");
    __builtin_amdgcn_sched_barrier(0);

    // Phase 3: accumulate in fp32.
    float acc[8];
    {
        const half8 hv = __builtin_bit_cast(half8, g[0]);
        const float w  = wts[0];
#pragma unroll
        for (int j = 0; j < 8; ++j) acc[j] = w * (float)hv[j];
    }
#pragma unroll
    for (int s = 1; s < S_DIM; ++s) {
        const half8 hv = __builtin_bit_cast(half8, g[s]);
        const float w  = wts[s];
#pragma unroll
        for (int j = 0; j < 8; ++j) acc[j] += w * (float)hv[j];
    }

    // LDS transpose so out stores are coalesced 128B segments over n.
    __shared__ float smem[64][33];
#pragma unroll
    for (int j = 0; j < 8; ++j) smem[nl][q * 8 + j] = acc[j];
    __syncthreads();

    const int f  = t >> 3;                    // 0..31
    const int c0 = t & 7;
#pragma unroll
    for (int k = 0; k < 2; ++k) {
        const int c = c0 + 8 * k;             // n quad 0..15
        f32x4 o;
        o.x = smem[c * 4 + 0][f];
        o.y = smem[c * 4 + 1][f];
        o.z = smem[c * 4 + 2][f];
        o.w = smem[c * 4 + 3][f];
        __builtin_nontemporal_store(
            o, (f32x4*)(out + ((size_t)bh * F_DIM + f) * N_DIM + nb + c * 4));
    }
}

// ---------------------------------------------------------------------------
// Fallback (only if ws too small): gather directly from [B,C,P] layout.
// ---------------------------------------------------------------------------
__global__ __launch_bounds__(256) void gather_direct_kernel(
    const float* __restrict__ lc, const int* __restrict__ idx,
    const float* __restrict__ conv, float* __restrict__ out) {
    const int t  = blockIdx.x * 256 + threadIdx.x;
    const int n  = t & (N_DIM - 1);
    const int bh = t >> 15;

    const float* Cb = conv + (size_t)bh * F_DIM * P_W3;
    const int*   ip = idx + (size_t)bh * S_DIM * N_DIM + n;
    const float* wp = lc  + (size_t)bh * S_DIM * N_DIM + n;

    float acc[F_DIM];
#pragma unroll
    for (int f = 0; f < F_DIM; ++f) acc[f] = 0.f;

#pragma unroll
    for (int s = 0; s < S_DIM; ++s) {
        const int   id = ip[(size_t)s * N_DIM];
        const float w  = wp[(size_t)s * N_DIM];
#pragma unroll
        for (int f = 0; f < F_DIM; ++f)
            acc[f] += w * Cb[(size_t)f * P_W3 + id];
    }

    float* op = out + (size_t)bh * F_DIM * N_DIM + n;
#pragma unroll
    for (int f = 0; f < F_DIM; ++f)
        op[(size_t)f * N_DIM] = acc[f];
}

extern "C" void kernel_launch(void* const* d_in, const int* in_sizes, int n_in,
                              void* d_out, int out_size, void* d_ws, size_t ws_size,
                              hipStream_t stream) {
    const float* lc   = (const float*)d_in[0];   // [B,H,S,N] fp32
    const int*   idx  = (const int*)d_in[1];     // [B,H,S,N] int32
    const float* conv = (const float*)d_in[2];   // [B,C,W,W,W] fp32
    float*       out  = (float*)d_out;           // [B,C,N] fp32

    const size_t need = (size_t)BH_DIM * P_W3 * F_DIM * sizeof(_Float16);  // 32 MiB
    if (ws_size >= need) {
        _Float16* T = (_Float16*)d_ws;
        transpose_f16_kernel<<<BH_DIM * (P_W3 / 64), 256, 0, stream>>>(conv, T);
        gather_f16_kernel<<<BH_DIM * (N_DIM / 64), 256, 0, stream>>>(lc, idx, T, out);
    } else {
        gather_direct_kernel<<<(BH_DIM * N_DIM) / 256, 256, 0, stream>>>(lc, idx, conv, out);
    }
}

// Round 7
// 161.039 us; speedup vs baseline: 1.0946x; 1.0946x over previous
//
#include <hip/hip_runtime.h>

// Problem constants (from reference setup_inputs):
//   B=4, H=4, S=8, N=32768, W=32 -> P=W^3=32768, C=128, F=C/H=32
#define P_W3 32768
#define F_DIM 32
#define S_DIM 8
#define N_DIM 32768
#define BH_DIM 16   // B*H
#define NXCD 8      // MI355X XCD count

typedef _Float16 half8 __attribute__((ext_vector_type(8)));  // 16 B
typedef float    f32x4 __attribute__((ext_vector_type(4)));  // 16 B, clang-native

// ---------------------------------------------------------------------------
// XCD-pinned bh decomposition: 8192 blocks = 16 bh x 512 tiles of 64.
//   xcd = blk & 7; slot = blk >> 3; bh = 2*xcd + (slot >> 9)
// Per-XCD live T working set = one 2 MiB bh slice (fits 4 MiB L2).
// Verified round 1: gather FETCH 133 -> 34 MB.
// ---------------------------------------------------------------------------
__device__ __forceinline__ void xcd_bh_tile(int blk, int& bh, int& tile) {
    const int xcd  = blk & (NXCD - 1);
    const int slot = blk >> 3;          // 0..1023
    bh   = 2 * xcd + (slot >> 9);       // 0..15
    tile = slot & 511;                  // 0..511
}

// ---------------------------------------------------------------------------
// Kernel 1: transpose + convert conv [bh, f, p] fp32 -> T [bh, p, f] fp16.
// Streaming-bound ~18 us vs ~15 us floor (96 MB at 6.3 TB/s) -- unchanged.
// ---------------------------------------------------------------------------
__global__ __launch_bounds__(256) void transpose_f16_kernel(
    const float* __restrict__ conv, _Float16* __restrict__ T) {
    int bh, pt;
    xcd_bh_tile(blockIdx.x, bh, pt);
    const int p0 = pt * 64;

    __shared__ float tile[F_DIM][65];         // stride 65: 2-way max on readout

    const float* src = conv + (size_t)bh * F_DIM * P_W3 + p0;
    {
        const int pp = (threadIdx.x & 15) * 4;
        const int f  = threadIdx.x >> 4;      // 0..15
#pragma unroll
        for (int k = 0; k < 2; ++k) {
            const f32x4 v = __builtin_nontemporal_load(
                (const f32x4*)(src + (size_t)(f + 16 * k) * P_W3 + pp));
            tile[f + 16 * k][pp + 0] = v.x;
            tile[f + 16 * k][pp + 1] = v.y;
            tile[f + 16 * k][pp + 2] = v.z;
            tile[f + 16 * k][pp + 3] = v.w;
        }
    }
    __syncthreads();

    _Float16* dst = T + ((size_t)bh * P_W3 + p0) * F_DIM;
    {
        const int f0 = (threadIdx.x & 3) * 8;
        const int p  = threadIdx.x >> 2;      // 0..63
        half8 hv;
#pragma unroll
        for (int j = 0; j < 8; ++j) hv[j] = (_Float16)tile[f0 + j][p];
        *(half8*)(dst + (size_t)p * F_DIM + f0) = hv;   // 64B/4 lanes contiguous
    }
}

// ---------------------------------------------------------------------------
// Kernel 2: gather -- R4 structure (verified best: ~39 us) + split drain.
// Structure rationale (rounds 2-6):
//   - idx/w staged via LDS by the COMPILER's own loads (R6 showed asm-forced
//     input loads get spilled between volatile asms -> re-serialized).
//   - only the 8 T-gathers are inline-asm forced (R4 verified: the only
//     structure the allocator cannot serialize). 32 dest VGPRs, no spill;
//     __launch_bounds__(256,4) gives the allocator a 128-VGPR cap so the
//     R6 spill mode cannot recur.
//   - split drain: vmcnt(4) -> FMA s0..3 -> vmcnt(0) -> FMA s4..7 overlaps
//     half the accumulate with the in-flight tail of the gather batch.
//     sched_barrier(0) after each waitcnt (rule #18) keeps consumers below.
// L2-BW floor for the gather phase: 1.07 GB / 34.5 TB/s ~= 31 us.
// ---------------------------------------------------------------------------
__global__ __launch_bounds__(256, 4) void gather_f16_kernel(
    const float* __restrict__ lc, const int* __restrict__ idx,
    const _Float16* __restrict__ T, float* __restrict__ out) {
    int bh, nt;
    xcd_bh_tile(blockIdx.x, bh, nt);
    const int nb = nt * 64;
    const int t  = threadIdx.x;
    const int q  = t & 3;                     // 16B sub-chunk 0..3
    const int nl = t >> 2;                    // local n 0..63

    __shared__ int   s_id[S_DIM][64];
    __shared__ float s_w [S_DIM][64];

    // Stage idx/w once per block: 512+512 elements, 256 threads -> 2+2
    // coalesced loads per thread, compiler-scheduled (batches fine).
    {
        const int*   ip0 = idx + (size_t)bh * S_DIM * N_DIM + nb;
        const float* wp0 = lc  + (size_t)bh * S_DIM * N_DIM + nb;
#pragma unroll
        for (int r = 0; r < 2; ++r) {
            const int e  = t + 256 * r;       // 0..511
            const int s  = e >> 6;            // 0..7
            const int nn = e & 63;
            s_id[s][nn] = __builtin_nontemporal_load(ip0 + (size_t)s * N_DIM + nn);
            s_w [s][nn] = __builtin_nontemporal_load(wp0 + (size_t)s * N_DIM + nn);
        }
    }
    __syncthreads();

    // This thread's 8 (id, w) pairs (4-lane broadcast LDS reads, no conflict).
    int   ids[S_DIM];
    float wts[S_DIM];
#pragma unroll
    for (int s = 0; s < S_DIM; ++s) {
        ids[s] = s_id[s][nl];
        wts[s] = s_w [s][nl];
    }

    // Issue all 8 gathers; distinct forced-live 4-VGPR dests. Wave-uniform
    // SGPR-pair base (per-bh T slice), 32-bit voffset per lane.
    const _Float16* Tbase = T + (size_t)bh * P_W3 * F_DIM;
    f32x4 g[S_DIM];
#pragma unroll
    for (int s = 0; s < S_DIM; ++s) {
        const int voff = (ids[s] << 6) + (q << 4);   // id*64B + q*16B
        asm volatile("global_load_dwordx4 %0, %1, %2"
                     : "=v"(g[s]) : "v"(voff), "s"(Tbase) : "memory");
    }

    float acc[8];

    // Oldest 4 gathers retired; last 4 still in flight during this FMA block.
    asm volatile("s_waitcnt vmcnt(4)" ::: "memory");
    __builtin_amdgcn_sched_barrier(0);
    {
        const half8 hv = __builtin_bit_cast(half8, g[0]);
        const float w  = wts[0];
#pragma unroll
        for (int j = 0; j < 8; ++j) acc[j] = w * (float)hv[j];
    }
#pragma unroll
    for (int s = 1; s < 4; ++s) {
        const half8 hv = __builtin_bit_cast(half8, g[s]);
        const float w  = wts[s];
#pragma unroll
        for (int j = 0; j < 8; ++j) acc[j] += w * (float)hv[j];
    }

    asm volatile("s_waitcnt vmcnt(0)" ::: "memory");
    __builtin_amdgcn_sched_barrier(0);
#pragma unroll
    for (int s = 4; s < S_DIM; ++s) {
        const half8 hv = __builtin_bit_cast(half8, g[s]);
        const float w  = wts[s];
#pragma unroll
        for (int j = 0; j < 8; ++j) acc[j] += w * (float)hv[j];
    }

    // LDS transpose so out stores are coalesced 128B segments over n.
    __shared__ float smem[64][33];
#pragma unroll
    for (int j = 0; j < 8; ++j) smem[nl][q * 8 + j] = acc[j];
    __syncthreads();

    const int f  = t >> 3;                    // 0..31
    const int c0 = t & 7;
#pragma unroll
    for (int k = 0; k < 2; ++k) {
        const int c = c0 + 8 * k;             // n quad 0..15
        f32x4 o;
        o.x = smem[c * 4 + 0][f];
        o.y = smem[c * 4 + 1][f];
        o.z = smem[c * 4 + 2][f];
        o.w = smem[c * 4 + 3][f];
        __builtin_nontemporal_store(
            o, (f32x4*)(out + ((size_t)bh * F_DIM + f) * N_DIM + nb + c * 4));
    }
}

// ---------------------------------------------------------------------------
// Fallback (only if ws too small): gather directly from [B,C,P] layout.
// ---------------------------------------------------------------------------
__global__ __launch_bounds__(256) void gather_direct_kernel(
    const float* __restrict__ lc, const int* __restrict__ idx,
    const float* __restrict__ conv, float* __restrict__ out) {
    const int t  = blockIdx.x * 256 + threadIdx.x;
    const int n  = t & (N_DIM - 1);
    const int bh = t >> 15;

    const float* Cb = conv + (size_t)bh * F_DIM * P_W3;
    const int*   ip = idx + (size_t)bh * S_DIM * N_DIM + n;
    const float* wp = lc  + (size_t)bh * S_DIM * N_DIM + n;

    float acc[F_DIM];
#pragma unroll
    for (int f = 0; f < F_DIM; ++f) acc[f] = 0.f;

#pragma unroll
    for (int s = 0; s < S_DIM; ++s) {
        const int   id = ip[(size_t)s * N_DIM];
        const float w  = wp[(size_t)s * N_DIM];
#pragma unroll
        for (int f = 0; f < F_DIM; ++f)
            acc[f] += w * Cb[(size_t)f * P_W3 + id];
    }

    float* op = out + (size_t)bh * F_DIM * N_DIM + n;
#pragma unroll
    for (int f = 0; f < F_DIM; ++f)
        op[(size_t)f * N_DIM] = acc[f];
}

extern "C" void kernel_launch(void* const* d_in, const int* in_sizes, int n_in,
                              void* d_out, int out_size, void* d_ws, size_t ws_size,
                              hipStream_t stream) {
    const float* lc   = (const float*)d_in[0];   // [B,H,S,N] fp32
    const int*   idx  = (const int*)d_in[1];     // [B,H,S,N] int32
    const float* conv = (const float*)d_in[2];   // [B,C,W,W,W] fp32
    float*       out  = (float*)d_out;           // [B,C,N] fp32

    const size_t need = (size_t)BH_DIM * P_W3 * F_DIM * sizeof(_Float16);  // 32 MiB
    if (ws_size >= need) {
        _Float16* T = (_Float16*)d_ws;
        transpose_f16_kernel<<<BH_DIM * (P_W3 / 64), 256, 0, stream>>>(conv, T);
        gather_f16_kernel<<<BH_DIM * (N_DIM / 64), 256, 0, stream>>>(lc, idx, T, out);
    } else {
        gather_direct_kernel<<<(BH_DIM * N_DIM) / 256, 256, 0, stream>>>(lc, idx, conv, out);
    }
}